// Round 4
// baseline (134.350 us; speedup 1.0000x reference)
//
#include <hip/hip_runtime.h>
#include <hip/hip_bf16.h>

#define NN 4096
#define DD 256
#define OO 256
#define YT 64
#define NSTEP 16

typedef __attribute__((ext_vector_type(4))) float f32x4;
typedef __attribute__((ext_vector_type(8))) short bf16x8;
typedef __attribute__((ext_vector_type(4))) unsigned int u32x4;

__device__ __forceinline__ short f2bfs(float f) {
    __hip_bfloat16 h = __float2bfloat16(f);
    short s;
    __builtin_memcpy(&s, &h, 2);
    return s;
}

__device__ __forceinline__ void gl_lds16(const float* gsrc, float* ldst) {
    __builtin_amdgcn_global_load_lds(
        (const __attribute__((address_space(1))) void*)gsrc,
        (__attribute__((address_space(3))) void*)ldst,
        16, 0, 0);
}

// K1: XWT[o][m] = sum_k X[m][k] * W[k][o], bf16, layout [OO][NN]. m-tile 8, 512 blocks.
__global__ __launch_bounds__(256) void k1_xwt(
    const float* __restrict__ X, const float* __restrict__ W,
    unsigned short* __restrict__ XWT)
{
    __shared__ float xs[8][DD];
    const int t = threadIdx.x;
    const int m0 = blockIdx.x * 8;

    #pragma unroll
    for (int i = 0; i < 8; ++i)
        xs[i][t] = X[(size_t)(m0 + i) * DD + t];
    __syncthreads();

    float acc[8];
    #pragma unroll
    for (int m = 0; m < 8; ++m) acc[m] = 0.f;

    for (int k0 = 0; k0 < DD; k0 += 4) {
        float w0 = W[(size_t)(k0 + 0) * OO + t];
        float w1 = W[(size_t)(k0 + 1) * OO + t];
        float w2 = W[(size_t)(k0 + 2) * OO + t];
        float w3 = W[(size_t)(k0 + 3) * OO + t];
        #pragma unroll
        for (int m = 0; m < 8; ++m) {
            const f32x4 xv = *reinterpret_cast<const f32x4*>(&xs[m][k0]);
            acc[m] = fmaf(xv[0], w0, acc[m]);
            acc[m] = fmaf(xv[1], w1, acc[m]);
            acc[m] = fmaf(xv[2], w2, acc[m]);
            acc[m] = fmaf(xv[3], w3, acc[m]);
        }
    }

    unsigned int p[4];
    #pragma unroll
    for (int i = 0; i < 4; ++i) {
        unsigned lo = (unsigned short)f2bfs(acc[2 * i]);
        unsigned hi = (unsigned short)f2bfs(acc[2 * i + 1]);
        p[i] = lo | (hi << 16);
    }
    *reinterpret_cast<u32x4*>(XWT + (size_t)t * NN + m0) = (u32x4){p[0], p[1], p[2], p[3]};
}

// K2: stage-ahead-2 ring pipeline. beta ring-4 (16KB), adj ring-3 (36KB).
// Per step stages 16 n-rows (beta 4KB + adj 12KB, 2 gl_lds16/thread = 2 VMEM/wave).
// Counted vmcnt(2) at barriers keeps one stage in flight across every barrier.
// MFMA (K=32) on odd steps, A-frag spanning buffers (st-1, st).
__global__ __launch_bounds__(512, 4) void k2_fused(
    const float* __restrict__ Beta, const unsigned short* __restrict__ XWT,
    const float* __restrict__ Adj,
    float* __restrict__ gpart, float* __restrict__ apart,
    int clen)
{
    __shared__ char smem[4 * NSTEP * YT * 4 + 3 * NSTEP * YT * 3 * 4];  // 52 KB
    float (*beta_s)[NSTEP][YT]     = reinterpret_cast<float (*)[NSTEP][YT]>(smem);
    float (*adj_s)[NSTEP][YT * 3]  = reinterpret_cast<float (*)[NSTEP][YT * 3]>(smem + 4 * NSTEP * YT * 4);

    const int t = threadIdx.x;
    const int lane = t & 63;
    const int w = t >> 6;
    const int wo = w & 1, wy = w >> 1;
    const int g16 = lane >> 4, r16 = lane & 15;
    const int tile = blockIdx.x, chunk = blockIdx.y;
    const int y0 = tile * YT;
    const int nbase = chunk * clen;
    const int nsteps = clen / NSTEP;

    // per-thread staging slots (constants): s0 = t (beta for t<256 else adj t-256), s1 = adj t+256
    const bool isb = (t < 256);
    const int b_row = t >> 4, b_off = (t & 15) * 4;
    const int a0 = isb ? 0 : (t - 256);
    const int a0_row = a0 / 48, a0_off = (a0 % 48) * 4;
    const int a1 = t + 256;
    const int a1_row = a1 / 48, a1_off = (a1 % 48) * 4;

    #define STAGE(q)                                                               \
        do {                                                                       \
            const int gq = nbase + (q) * NSTEP;                                    \
            if (isb)                                                               \
                gl_lds16(Beta + (size_t)(gq + b_row) * NN + y0 + b_off,            \
                         &beta_s[(q) & 3][b_row][b_off]);                          \
            else                                                                   \
                gl_lds16(Adj + ((size_t)(gq + a0_row) * NN + y0) * 3 + a0_off,     \
                         &adj_s[(q) % 3][a0_row][a0_off]);                         \
            gl_lds16(Adj + ((size_t)(gq + a1_row) * NN + y0) * 3 + a1_off,         \
                     &adj_s[(q) % 3][a1_row][a1_off]);                             \
        } while (0)

    #define BAR2() do { asm volatile("s_waitcnt vmcnt(2)" ::: "memory");           \
                        __builtin_amdgcn_s_barrier();                              \
                        __builtin_amdgcn_sched_barrier(0); } while (0)
    #define BAR0() do { asm volatile("s_waitcnt vmcnt(0)" ::: "memory");           \
                        __builtin_amdgcn_s_barrier();                              \
                        __builtin_amdgcn_sched_barrier(0); } while (0)

    // adjacency partial for step st: wave w owns rows 2w, 2w+1; lane = y
    #define ADJC(st)                                                               \
        do {                                                                       \
            const float* bp = &beta_s[(st) & 3][2 * w][0];                         \
            const float* ap = &adj_s[(st) % 3][2 * w][0];                          \
            const float bv0 = bp[lane], bv1 = bp[YT + lane];                       \
            ag0 = fmaf(bv0, ap[lane * 3 + 0], ag0);                                \
            ag1 = fmaf(bv0, ap[lane * 3 + 1], ag1);                                \
            ag2 = fmaf(bv0, ap[lane * 3 + 2], ag2);                                \
            ag0 = fmaf(bv1, ap[YT * 3 + lane * 3 + 0], ag0);                       \
            ag1 = fmaf(bv1, ap[YT * 3 + lane * 3 + 1], ag1);                       \
            ag2 = fmaf(bv1, ap[YT * 3 + lane * 3 + 2], ag2);                       \
        } while (0)

    f32x4 acc[8];
    #pragma unroll
    for (int i = 0; i < 8; ++i) acc[i] = (f32x4){0.f, 0.f, 0.f, 0.f};
    float ag0 = 0.f, ag1 = 0.f, ag2 = 0.f;

    const unsigned short* xwb = XWT + (size_t)(128 * wo + r16) * NN + nbase + 8 * g16;

    // prologue: two stages in flight, publish stage 0, keep stage 1 flying
    STAGE(0);
    STAGE(1);
    asm volatile("s_waitcnt vmcnt(2)" ::: "memory");
    __builtin_amdgcn_s_barrier();
    __builtin_amdgcn_sched_barrier(0);

    for (int p = 0; p < nsteps / 2; ++p) {
        const int se = 2 * p, so = se + 1;

        // ---- even step: stage(se+2), adjacency only ----
        if (se + 2 < nsteps) {
            STAGE(se + 2);
            ADJC(se);
            BAR2();          // stage(se+1) done, stage(se+2) stays in flight
        } else {
            ADJC(se);
            BAR0();          // tail: publish last stage
        }

        // ---- odd step: bf loads FIRST (vmcnt-queue order!), then stage(so+2) ----
        bf16x8 bf[8];
        const unsigned short* xp = xwb + se * NSTEP;
        #pragma unroll
        for (int of = 0; of < 8; ++of)
            bf[of] = *reinterpret_cast<const bf16x8*>(xp + (size_t)of * 16 * NN);

        if (so + 2 < nsteps) STAGE(so + 2);

        ADJC(so);

        // A-frag spans buffers (se, so): k = 8*g16 + j
        {
            const int bufe = se & 3, bufo = so & 3;
            const float* bcol = (g16 < 2)
                ? &beta_s[bufe][8 * g16][16 * wy + r16]
                : &beta_s[bufo][8 * g16 - 16][16 * wy + r16];
            bf16x8 av;
            #pragma unroll
            for (int j = 0; j < 8; ++j)
                av[j] = f2bfs(bcol[(size_t)j * YT]);
            #pragma unroll
            for (int of = 0; of < 8; ++of)
                acc[of] = __builtin_amdgcn_mfma_f32_16x16x32_bf16(av, bf[of], acc[of], 0, 0, 0);
        }

        if (p + 1 < nsteps / 2) {
            if (so + 2 < nsteps) BAR2(); else BAR0();
        }
    }

    // ---- epilogue ----
    __syncthreads();
    float (*lagg)[YT][3] = reinterpret_cast<float (*)[YT][3]>(smem);  // alias (loop done)
    lagg[w][lane][0] = ag0;
    lagg[w][lane][1] = ag1;
    lagg[w][lane][2] = ag2;
    __syncthreads();
    if (t < YT * 3) {
        const int yy = t / 3, cc = t % 3;
        float s = 0.f;
        #pragma unroll
        for (int g = 0; g < 8; ++g) s += lagg[g][yy][cc];
        apart[((size_t)chunk * (NN / YT) + tile) * (YT * 3) + t] = s;
    }

    float* gp = gpart + ((size_t)chunk * NN + y0) * OO;
    #pragma unroll
    for (int of = 0; of < 8; ++of) {
        const int o = 128 * wo + 16 * of + r16;
        #pragma unroll
        for (int r = 0; r < 4; ++r) {
            const int yl = 16 * wy + 4 * g16 + r;
            gp[(size_t)yl * OO + o] = acc[of][r];
        }
    }
    #undef STAGE
    #undef BAR2
    #undef BAR0
    #undef ADJC
}

// K3: out[y,o] = sum_ch gpart + (sum_ch apart[y]) @ Wa + bias
__global__ __launch_bounds__(256) void k3_reduce(
    const float* __restrict__ gpart, const float* __restrict__ apart,
    const float* __restrict__ W, const float* __restrict__ bias,
    float* __restrict__ Out, int nchunk)
{
    const int idx = blockIdx.x * 256 + threadIdx.x;   // 0 .. NN*OO/4-1
    const int o = (idx << 2) & (OO - 1);
    const int y = idx >> 6;

    f32x4 acc = {0.f, 0.f, 0.f, 0.f};
    for (int ch = 0; ch < nchunk; ++ch) {
        const f32x4 g = *reinterpret_cast<const f32x4*>(
            &gpart[((size_t)ch * NN + y) * OO + o]);
        acc[0] += g[0]; acc[1] += g[1]; acc[2] += g[2]; acc[3] += g[3];
    }

    float a0 = 0.f, a1 = 0.f, a2 = 0.f;
    const int tile = y >> 6, yl = y & 63;
    for (int ch = 0; ch < nchunk; ++ch) {
        const float* ap = apart + ((size_t)ch * (NN / YT) + tile) * (YT * 3) + yl * 3;
        a0 += ap[0]; a1 += ap[1]; a2 += ap[2];
    }

    #pragma unroll
    for (int j = 0; j < 4; ++j) {
        const int oo = o + j;
        Out[(size_t)y * OO + oo] = acc[j]
            + a0 * W[(size_t)(DD + 0) * OO + oo]
            + a1 * W[(size_t)(DD + 1) * OO + oo]
            + a2 * W[(size_t)(DD + 2) * OO + oo]
            + bias[oo];
    }
}

extern "C" void kernel_launch(void* const* d_in, const int* in_sizes, int n_in,
                              void* d_out, int out_size, void* d_ws, size_t ws_size,
                              hipStream_t stream) {
    (void)in_sizes; (void)n_in; (void)out_size;
    const float* adj  = (const float*)d_in[0];  // (N, N, C)
    const float* X    = (const float*)d_in[1];  // (N, D)
    const float* Beta = (const float*)d_in[2];  // (N, N)
    const float* W    = (const float*)d_in[3];  // (D+C, O)
    const float* bias = (const float*)d_in[4];  // (O)
    float* out = (float*)d_out;                 // (N, O) fp32

    unsigned short* XWT = (unsigned short*)d_ws;       // bf16 [OO][NN], 2 MB
    const size_t xwt_bytes = (size_t)OO * NN * 2;

    const size_t per_chunk = (size_t)NN * OO * 4 + (size_t)(NN / YT) * YT * 3 * 4;
    int nchunk = 4;
    if (ws_size >= xwt_bytes + 16 * per_chunk) nchunk = 16;
    else if (ws_size >= xwt_bytes + 8 * per_chunk) nchunk = 8;
    const int clen = NN / nchunk;

    float* gpart = (float*)((char*)d_ws + xwt_bytes);
    float* apart = (float*)((char*)d_ws + xwt_bytes + (size_t)nchunk * NN * OO * 4);

    k1_xwt<<<dim3(NN / 8), dim3(256), 0, stream>>>(X, W, XWT);
    k2_fused<<<dim3(NN / YT, nchunk), dim3(512), 0, stream>>>(
        Beta, XWT, adj, gpart, apart, clen);
    k3_reduce<<<dim3(NN * OO / 4 / 256), dim3(256), 0, stream>>>(
        gpart, apart, W, bias, out, nchunk);
}